// Round 3
// baseline (3775.230 us; speedup 1.0000x reference)
//
#include <hip/hip_runtime.h>
#include <hip/hip_bf16.h>

#define N_NODES 50000
#define N_EDGES 400000
#define SLOPE 0.2f

static __device__ __forceinline__ float lrelu(float x) { return x >= 0.f ? x : SLOPE * x; }
static __device__ __forceinline__ float b2f(__hip_bfloat16 x) { return __bfloat162float(x); }
static __device__ __forceinline__ int clampi(int v, int lo, int hi) {
    return v < lo ? lo : (v > hi ? hi : v);
}
// dual-dtype float load: isb ? bf16 : f32
static __device__ __forceinline__ float ldF(const void* __restrict__ p, size_t i, bool isb) {
    return isb ? b2f(((const __hip_bfloat16*)p)[i]) : ((const float*)p)[i];
}
// dual-width index load: i64 ? int64 : int32
static __device__ __forceinline__ int ldI(const void* __restrict__ p, size_t i, bool i64) {
    return i64 ? (int)(((const long long*)p)[i]) : ((const int*)p)[i];
}

// ---------------- K0: dtype detection ----------------------------------------------------
__global__ void k_detect(const void* __restrict__ nf, const void* __restrict__ eidx,
                         int* __restrict__ flags)
{
    int t = threadIdx.x;  // 64 threads
    // float dtype: read bf16 at even indices. True bf16 data ~N(0,1): always sane.
    // f32-read-as-bf16 (mantissa words): random exponent -> huge/nonfinite w.h.p.
    float x = b2f(((const __hip_bfloat16*)nf)[2 * t]);
    bool bad = !(x == x) || fabsf(x) > 1e4f;
    unsigned long long fmask = __ballot(bad);
    // int width: odd int32 words of edge_index. int64 data (values < 50000): all zero.
    int v = ((const int*)eidx)[2 * t + 1];
    unsigned long long imask = __ballot(v != 0);
    if (t == 0) {
        flags[0] = (fmask == 0ull) ? 1 : 0;  // 1 => floats are bf16
        flags[1] = (imask == 0ull) ? 1 : 0;  // 1 => ints are int64
    }
}

// ---------------- K1: typed node embedding ------------------------------------------------
__global__ __launch_bounds__(128) void k_node_emb(
    const void* __restrict__ nf, const void* __restrict__ ntype,
    const void* __restrict__ Wn, __hip_bfloat16* __restrict__ node_emb,
    const int* __restrict__ flags)
{
    const bool isb = flags[0] != 0, i64 = flags[1] != 0;
    int n = blockIdx.x, t = threadIdx.x;
    __shared__ float x[256];
    x[t]       = ldF(nf, (size_t)n * 256 + t, isb);
    x[128 + t] = ldF(nf, (size_t)n * 256 + 128 + t, isb);
    __syncthreads();
    int ty = clampi(ldI(ntype, n, i64), 0, 2);
    float acc = 0.f;
    if (isb) {
        const __hip_bfloat16* W = (const __hip_bfloat16*)Wn + (size_t)ty * 256 * 128;
        #pragma unroll 4
        for (int i = 0; i < 256; ++i) acc += x[i] * b2f(W[(size_t)i * 128 + t]);
    } else {
        const float* W = (const float*)Wn + (size_t)ty * 256 * 128;
        #pragma unroll 4
        for (int i = 0; i < 256; ++i) acc += x[i] * W[(size_t)i * 128 + t];
    }
    node_emb[(size_t)n * 128 + t] = __float2bfloat16(acc);
}

// ---------------- K2: per-edge attention scores -------------------------------------------
#define EPB 8
__global__ __launch_bounds__(128) void k_edge_scores(
    const void* __restrict__ eattr, const void* __restrict__ etype,
    const void* __restrict__ eidx, const __hip_bfloat16* __restrict__ node_emb,
    const void* __restrict__ Wea, const void* __restrict__ Wet,
    const void* __restrict__ Wat, float* __restrict__ scores,
    const int* __restrict__ flags)
{
    const bool isb = flags[0] != 0, i64 = flags[1] != 0;
    int t = threadIdx.x;
    __shared__ float wat[512 * 8];
    __shared__ float ea[64], et[64];
    __shared__ float feat[512];
    for (int i = t; i < 512 * 8; i += 128) wat[i] = ldF(Wat, i, isb);
    int e0 = blockIdx.x * EPB;
    int h = t >> 4, g = t & 15;
    for (int r = 0; r < EPB; ++r) {
        int e = e0 + r;                       // E % EPB == 0
        int s = clampi(ldI(eidx, e, i64), 0, N_NODES - 1);
        int d = clampi(ldI(eidx, (size_t)N_EDGES + e, i64), 0, N_NODES - 1);
        if (t < 64) {
            ea[t] = ldF(eattr, (size_t)e * 64 + t, isb);
            et[t] = ldF(etype, (size_t)e * 64 + t, isb);
        }
        feat[t]       = b2f(node_emb[(size_t)d * 128 + t]);   // tar_emb
        feat[384 + t] = b2f(node_emb[(size_t)s * 128 + t]);   // src_emb
        __syncthreads();
        float a = 0.f, b = 0.f;
        if (isb) {
            const __hip_bfloat16* WA = (const __hip_bfloat16*)Wea;
            const __hip_bfloat16* WT = (const __hip_bfloat16*)Wet;
            #pragma unroll 4
            for (int k = 0; k < 64; ++k) {
                a += ea[k] * b2f(WA[(size_t)k * 128 + t]);
                b += et[k] * b2f(WT[(size_t)k * 128 + t]);
            }
        } else {
            const float* WA = (const float*)Wea;
            const float* WT = (const float*)Wet;
            #pragma unroll 4
            for (int k = 0; k < 64; ++k) {
                a += ea[k] * WA[(size_t)k * 128 + t];
                b += et[k] * WT[(size_t)k * 128 + t];
            }
        }
        feat[128 + t] = lrelu(a);
        feat[256 + t] = lrelu(b);
        __syncthreads();
        float p = 0.f;
        #pragma unroll
        for (int k = 0; k < 32; ++k) {
            int i = g + 16 * k;
            p += feat[i] * wat[i * 8 + h];
        }
        p += __shfl_down(p, 8, 16);
        p += __shfl_down(p, 4, 16);
        p += __shfl_down(p, 2, 16);
        p += __shfl_down(p, 1, 16);
        if (g == 0) scores[(size_t)e * 8 + h] = lrelu(p);
        __syncthreads();
    }
}

// ---------------- K3: CSR build over src --------------------------------------------------
__global__ void k_hist(const void* __restrict__ eidx, int* __restrict__ counts,
                       const int* __restrict__ flags)
{
    const bool i64 = flags[1] != 0;
    int e = blockIdx.x * blockDim.x + threadIdx.x;
    if (e < N_EDGES) atomicAdd(&counts[clampi(ldI(eidx, e, i64), 0, N_NODES - 1)], 1);
}

__global__ __launch_bounds__(256) void k_scan(const int* __restrict__ counts, int* __restrict__ offsets)
{
    __shared__ int buf[256];
    __shared__ int s_running;
    int t = threadIdx.x;
    if (t == 0) s_running = 0;
    __syncthreads();
    for (int base = 0; base < N_NODES; base += 256) {
        int i = base + t;
        int v = (i < N_NODES) ? counts[i] : 0;
        buf[t] = v;
        __syncthreads();
        for (int d = 1; d < 256; d <<= 1) {
            int add = (t >= d) ? buf[t - d] : 0;
            __syncthreads();
            buf[t] += add;
            __syncthreads();
        }
        int incl = buf[t];
        int run = s_running;
        __syncthreads();
        if (i < N_NODES) offsets[i] = run + incl - v;
        if (t == 255) s_running = run + buf[255];
        __syncthreads();
    }
    if (t == 0) offsets[N_NODES] = s_running;
}

__global__ void k_scatter(const void* __restrict__ eidx, const int* __restrict__ offsets,
                          int* __restrict__ fill, int* __restrict__ perm,
                          const int* __restrict__ flags)
{
    const bool i64 = flags[1] != 0;
    int e = blockIdx.x * blockDim.x + threadIdx.x;
    if (e >= N_EDGES) return;
    int s = clampi(ldI(eidx, e, i64), 0, N_NODES - 1);
    int p = atomicAdd(&fill[s], 1);
    perm[offsets[s] + p] = e;
}

// ---------------- K4: segment softmax stats (max, denom) per (node, head) -----------------
__global__ void k_stats(const float* __restrict__ scores, const int* __restrict__ offsets,
                        const int* __restrict__ counts, const int* __restrict__ perm,
                        float* __restrict__ stats)
{
    int tid = blockIdx.x * blockDim.x + threadIdx.x;
    if (tid >= N_NODES * 8) return;
    int n = tid >> 3, h = tid & 7;
    int off = offsets[n], deg = counts[n];
    if (deg == 0) { stats[n * 16 + h] = 0.f; stats[n * 16 + 8 + h] = 1.f; return; }
    float m = -1e30f;
    for (int j = 0; j < deg; ++j) {
        int e = clampi(perm[off + j], 0, N_EDGES - 1);
        m = fmaxf(m, scores[(size_t)e * 8 + h]);
    }
    float d = 0.f;
    for (int j = 0; j < deg; ++j) {
        int e = clampi(perm[off + j], 0, N_EDGES - 1);
        d += expf(scores[(size_t)e * 8 + h] - m);
    }
    stats[n * 16 + h] = m;
    stats[n * 16 + 8 + h] = (d > 0.f) ? d : 1.f;
}

// ---------------- K5: per-node aggregation ------------------------------------------------
__global__ __launch_bounds__(128) void k_aggr(
    const __hip_bfloat16* __restrict__ node_emb, const float* __restrict__ stats,
    const float* __restrict__ scores, const int* __restrict__ offsets,
    const int* __restrict__ counts, const int* __restrict__ perm,
    const void* __restrict__ eattr, const void* __restrict__ Wea,
    const void* __restrict__ Wup, void* __restrict__ out,
    const int* __restrict__ flags)
{
    const bool isb = flags[0] != 0;
    int n = blockIdx.x, t = threadIdx.x;
    __shared__ float xe[128], ea[64], ae[128], attn[8], mh[8], invd[8];
    xe[t] = b2f(node_emb[(size_t)n * 128 + t]);
    if (t < 8) {
        mh[t] = stats[n * 16 + t];
        float dn = stats[n * 16 + 8 + t];
        invd[t] = (dn > 0.f) ? 1.f / dn : 0.f;
    }
    __syncthreads();
    float base = 0.f;
    if (isb) {
        const __hip_bfloat16* W = (const __hip_bfloat16*)Wup;
        #pragma unroll 4
        for (int i = 0; i < 128; ++i) base += xe[i] * b2f(W[(size_t)i * 128 + t]);
    } else {
        const float* W = (const float*)Wup;
        #pragma unroll 4
        for (int i = 0; i < 128; ++i) base += xe[i] * W[(size_t)i * 128 + t];
    }
    float acc[8];
    #pragma unroll
    for (int h = 0; h < 8; ++h) acc[h] = 0.f;
    int off = offsets[n], deg = counts[n];
    for (int j = 0; j < deg; ++j) {
        int e = clampi(perm[off + j], 0, N_EDGES - 1);
        if (t < 64) ea[t] = ldF(eattr, (size_t)e * 64 + t, isb);
        if (t < 8)  attn[t] = expf(scores[(size_t)e * 8 + t] - mh[t]) * invd[t];
        __syncthreads();
        float a = 0.f;
        if (isb) {
            const __hip_bfloat16* WA = (const __hip_bfloat16*)Wea;
            #pragma unroll 4
            for (int k = 0; k < 64; ++k) a += ea[k] * b2f(WA[(size_t)k * 128 + t]);
        } else {
            const float* WA = (const float*)Wea;
            #pragma unroll 4
            for (int k = 0; k < 64; ++k) a += ea[k] * WA[(size_t)k * 128 + t];
        }
        ae[t] = lrelu(a);
        __syncthreads();
        float m = base;
        if (isb) {
            const __hip_bfloat16* W = (const __hip_bfloat16*)Wup;
            #pragma unroll 4
            for (int i = 0; i < 128; ++i) m += ae[i] * b2f(W[(size_t)(128 + i) * 128 + t]);
        } else {
            const float* W = (const float*)Wup;
            #pragma unroll 4
            for (int i = 0; i < 128; ++i) m += ae[i] * W[(size_t)(128 + i) * 128 + t];
        }
        m = lrelu(m);
        #pragma unroll
        for (int h = 0; h < 8; ++h) acc[h] += attn[h] * m;
        __syncthreads();
    }
    // output dtype follows the float-input dtype (harness converts all-or-nothing)
    if (isb) {
        __hip_bfloat16* o = (__hip_bfloat16*)out;
        #pragma unroll
        for (int h = 0; h < 8; ++h)
            o[(size_t)n * 1024 + h * 128 + t] = __float2bfloat16(acc[h]);
    } else {
        float* o = (float*)out;
        #pragma unroll
        for (int h = 0; h < 8; ++h)
            o[(size_t)n * 1024 + h * 128 + t] = acc[h];
    }
}

// ---------------- launcher ----------------------------------------------------------------
extern "C" void kernel_launch(void* const* d_in, const int* in_sizes, int n_in,
                              void* d_out, int out_size, void* d_ws, size_t ws_size,
                              hipStream_t stream)
{
    const void* nf   = d_in[0];
    const void* eidx = d_in[1];
    const void* eatt = d_in[2];
    const void* etyp = d_in[3];
    const void* ntyp = d_in[4];
    // d_in[5] edge_type_list: unused by the reference
    const void* Wn   = d_in[6];
    const void* Wea  = d_in[7];
    const void* Wet  = d_in[8];
    const void* Wup  = d_in[9];
    const void* Wat  = d_in[10];

    // workspace layout (~31 MB total)
    int* flags = (int*)d_ws;                                            // 4 ints (16 B)
    __hip_bfloat16* node_emb = (__hip_bfloat16*)((char*)d_ws + 16);     // N*128 bf16
    float* scores  = (float*)(node_emb + (size_t)N_NODES * 128);        // E*8 f32
    float* stats   = scores + (size_t)N_EDGES * 8;                      // N*16 f32
    int*   counts  = (int*)(stats + (size_t)N_NODES * 16);              // N
    int*   offsets = counts + N_NODES;                                  // N+1
    int*   fill    = offsets + N_NODES + 1;                             // N
    int*   perm    = fill + N_NODES;                                    // E

    hipMemsetAsync(counts, 0, N_NODES * sizeof(int), stream);
    hipMemsetAsync(fill, 0, N_NODES * sizeof(int), stream);

    k_detect<<<1, 64, 0, stream>>>(nf, eidx, flags);
    k_node_emb<<<N_NODES, 128, 0, stream>>>(nf, ntyp, Wn, node_emb, flags);
    k_edge_scores<<<N_EDGES / EPB, 128, 0, stream>>>(eatt, etyp, eidx, node_emb,
                                                     Wea, Wet, Wat, scores, flags);
    k_hist<<<(N_EDGES + 255) / 256, 256, 0, stream>>>(eidx, counts, flags);
    k_scan<<<1, 256, 0, stream>>>(counts, offsets);
    k_scatter<<<(N_EDGES + 255) / 256, 256, 0, stream>>>(eidx, offsets, fill, perm, flags);
    k_stats<<<(N_NODES * 8 + 255) / 256, 256, 0, stream>>>(scores, offsets, counts, perm, stats);
    k_aggr<<<N_NODES, 128, 0, stream>>>(node_emb, stats, scores, offsets, counts, perm,
                                        eatt, Wea, Wup, d_out, flags);
}